// Round 8
// baseline (176.840 us; speedup 1.0000x reference)
//
#include <hip/hip_runtime.h>

#define VQ_EPS    1e-12f
#define VQ_WINDOW 0.01f     // >= ~14 sigma of the bf16 score error; proven R6-R10 (absmax 0)
#define VQ_CAP    10        // slimmed from 12 (u16 slist); overflow -> exact-scan path

typedef short bf16x8 __attribute__((ext_vector_type(8)));   // 8 bf16 bit-patterns = 4 VGPRs
typedef float f32x4  __attribute__((ext_vector_type(4)));

static __device__ __forceinline__ unsigned short f2bf(float f) {
    unsigned u = __float_as_uint(f);
    u += 0x7fffu + ((u >> 16) & 1u);     // RNE
    return (unsigned short)(u >> 16);
}

// Order-preserving float->uint map (handles negative exact scores).
static __device__ __forceinline__ unsigned f2ord(float f) {
    unsigned b = __float_as_uint(f);
    return (b & 0x80000000u) ? ~b : (b | 0x80000000u);
}

// Wave-local LDS fence (proven R14, absmax 0): drains this wave's DS ops and
// stops compiler reordering. Sufficient for slot traffic produced AND
// consumed by the same wave (all of scnt/slist/spack -- indices derive from
// wid only).
static __device__ __forceinline__ void wave_lds_fence() {
    asm volatile("s_waitcnt lgkmcnt(0)" ::: "memory");
}

// Prep kernel: normalize codebook rows (fp32, mirrors F.normalize), emit:
//   cbn  [512][64] fp32      -- exact rescore + codes-gather epilogue
//   cbB  [32 ntile][2 kstep][64 lane][8] bf16 -- B-fragment-linear for
//        mfma_f32_16x16x32_bf16 (layout proven correct R5-R10)
//   kn2  [512] fp32          -- sum(cbn^2) AFTER normalization (reference rounding)
//   kn2p [512] fp32          -- kn2 + 2.0f (keeps approx scores > 0 for uint packing)
__global__ __launch_bounds__(64) void cb_prep_kernel(const float* __restrict__ cb,
                                                     float* __restrict__ cbn,
                                                     unsigned short* __restrict__ cbB,
                                                     float* __restrict__ kn2,
                                                     float* __restrict__ kn2p) {
    const int k = blockIdx.x;       // 512 codes
    const int c = threadIdx.x;      // 64 channels
    float v = cb[k * 64 + c];
    float s = v * v;
    #pragma unroll
    for (int off = 32; off > 0; off >>= 1) s += __shfl_xor(s, off, 64);
    float n = sqrtf(s);
    float cn = v / fmaxf(n, VQ_EPS);
    cbn[k * 64 + c] = cn;

    const int ntile = k >> 4, col = k & 15;
    const int ks = c >> 5, quad = (c >> 3) & 3, j = c & 7;
    cbB[(((ntile * 2 + ks) * 64) + quad * 16 + col) * 8 + j] = f2bf(cn);

    float s2 = cn * cn;
    #pragma unroll
    for (int off = 32; off > 0; off >>= 1) s2 += __shfl_xor(s2, off, 64);
    if (c == 0) { kn2[k] = s2; kn2p[k] = s2 + 2.0f; }
}

// Main kernel R18: 256 blocks x 1024 thr (16 waves = 4 groups of 4), each
// wave fused-scans TWO rows over shared B-reads -- R17's fusion (proven
// absmax 0, 56 VGPR) repackaged at FULL occupancy (2 blocks/CU = 32
// waves/CU, vs R17's 16). Per-CU scan LDS traffic halves vs R13 (each 64 KB
// wave-sweep serves 2 rows) without R17's TLP loss. Additional fixes:
//   * per-row fallback flags (R17 OR'd both rows -> ~2x fallback cost);
//     uniform per-row branches inside the fallback loop.
//   * nt-rotation stagger: wave wr starts its sweep at nt offset wr*8 --
//     identical scores, order-independent pushes, de-correlates the
//     lockstepped waves' LDS/VALU bursts within a SIMD.
//   * LDS slimmed to 80 KB/block (slist u16, CAP 12->10; overflow uses the
//     proven exact-scan path) so 2 x 80 KB = 160 KB = full CU LDS.
// Safety recipe (R8/R9/R14, proven): shfls/ballot only in uniform code;
// slot init + candidate pushes wave-owned; rescore per-lane only;
// wave-local fences for same-wave slot traffic; B0 covers staging.
__global__ __launch_bounds__(1024, 8) void vq_mfma_kernel(const float* __restrict__ x,
                                                      const float* __restrict__ cbn,
                                                      const unsigned short* __restrict__ cbB,
                                                      const float* __restrict__ kn2,
                                                      const float* __restrict__ kn2p,
                                                      float* __restrict__ codes,
                                                      float* __restrict__ idxout) {
    __shared__ __align__(16) unsigned short lcb[32768];   // 64 KB staged cbB
    __shared__ unsigned long long spack[512];             // 4 KB
    __shared__ unsigned short slist[512][VQ_CAP];         // 10 KB
    __shared__ int scnt[512];                             // 2 KB   -> 80 KB total

    const int t    = threadIdx.x;
    const int lane = t & 63;
    const int wid  = t >> 6;          // 0..15
    const int col  = lane & 15;
    const int quad = lane >> 4;
    const int wr   = wid & 3;         // wave within its group
    const int grp  = wid >> 2;        // 0..3: row-pair of the block
    const int wpix = wr * 16 + col;   // col-group's pixel (w coordinate)

    const int rw0 = grp * 2;          // rows-within-block (8 rows/block)
    const int pbase0 = rw0 * 64;      // LDS pixel-slot bases
    const int pbase1 = pbase0 + 64;
    const int pslot0 = pbase0 + wpix;
    const int pslot1 = pbase1 + wpix;

    const int rowid0 = blockIdx.x * 8 + rw0;   // 0..2047 = (b,h)
    const int rowid1 = rowid0 + 1;
    const int b0r = rowid0 >> 6, h0 = rowid0 & 63;
    const int b1r = rowid1 >> 6, h1 = rowid1 & 63;
    const float* xblk0 = x + ((size_t)b0r << 18) + (h0 << 6);   // + c*4096 + w
    const float* xblk1 = x + ((size_t)b1r << 18) + (h1 << 6);

    if (quad == 0) {
        scnt[pslot0] = 0; spack[pslot0] = 0xFFFFFFFFFFFFFFFFull;
        scnt[pslot1] = 0; spack[pslot1] = 0xFFFFFFFFFFFFFFFFull;
    }

    // ---- gathers for BOTH rows issued up front (32 loads in flight;
    //      latency hides under the cbB staging + barrier) ----
    float xv0[16], xv1[16];
    #pragma unroll
    for (int ks = 0; ks < 2; ++ks)
        #pragma unroll
        for (int j = 0; j < 8; ++j)
            xv0[ks * 8 + j] = xblk0[(size_t)(ks * 32 + quad * 8 + j) * 4096 + wpix];
    #pragma unroll
    for (int ks = 0; ks < 2; ++ks)
        #pragma unroll
        for (int j = 0; j < 8; ++j)
            xv1[ks * 8 + j] = xblk1[(size_t)(ks * 32 + quad * 8 + j) * 4096 + wpix];

    // ---- stage cbB -> LDS: 1024 thr x 4 x 16 B, linear, coalesced ----
    {
        const uint4* g4 = (const uint4*)cbB;
        uint4*       l4 = (uint4*)lcb;
        #pragma unroll
        for (int r = 0; r < 4; ++r) l4[r * 1024 + t] = g4[r * 1024 + t];
    }

    __syncthreads();   // B0: staged cbB (and slot init) visible to all 16 waves

    // ---- prologs: norms + A fragments for both rows ----
    float ssp0 = 0.0f, ssp1 = 0.0f;
    #pragma unroll
    for (int i = 0; i < 16; ++i) ssp0 = fmaf(xv0[i], xv0[i], ssp0);
    #pragma unroll
    for (int i = 0; i < 16; ++i) ssp1 = fmaf(xv1[i], xv1[i], ssp1);
    ssp0 += __shfl_xor(ssp0, 16);    // uniform code: all 64 lanes execute
    ssp0 += __shfl_xor(ssp0, 32);
    ssp1 += __shfl_xor(ssp1, 16);
    ssp1 += __shfl_xor(ssp1, 32);
    const float m2a0 = -2.0f * (1.0f / fmaxf(sqrtf(ssp0), VQ_EPS));
    const float m2a1 = -2.0f * (1.0f / fmaxf(sqrtf(ssp1), VQ_EPS));
    float m2r0[4], m2r1[4];
    #pragma unroll
    for (int r = 0; r < 4; ++r) m2r0[r] = __shfl(m2a0, quad * 4 + r);  // uniform
    #pragma unroll
    for (int r = 0; r < 4; ++r) m2r1[r] = __shfl(m2a1, quad * 4 + r);
    const float m2P0 = __shfl(m2a0, lane >> 2);   // uniform: rescore-pixel m2
    const float m2P1 = __shfl(m2a1, lane >> 2);

    bf16x8 afrag0[2], afrag1[2];
    #pragma unroll
    for (int ks = 0; ks < 2; ++ks)
        #pragma unroll
        for (int j = 0; j < 8; ++j) {
            ((unsigned short*)&afrag0[ks])[j] = f2bf(xv0[ks * 8 + j]);
            ((unsigned short*)&afrag1[ks])[j] = f2bf(xv1[ks * 8 + j]);
        }

    const bf16x8* lBf = (const bf16x8*)lcb;
    const int ntoff = wr * 8;        // per-wave sweep rotation (stagger)

    // ---- fused pass 1: one B-read pair feeds BOTH rows' MFMAs ----
    unsigned run1_0[4] = {0xFFFFFFFFu, 0xFFFFFFFFu, 0xFFFFFFFFu, 0xFFFFFFFFu};
    unsigned run2_0[4] = {0xFFFFFFFFu, 0xFFFFFFFFu, 0xFFFFFFFFu, 0xFFFFFFFFu};
    unsigned run1_1[4] = {0xFFFFFFFFu, 0xFFFFFFFFu, 0xFFFFFFFFu, 0xFFFFFFFFu};
    unsigned run2_1[4] = {0xFFFFFFFFu, 0xFFFFFFFFu, 0xFFFFFFFFu, 0xFFFFFFFFu};
    #pragma unroll 2
    for (int nt = 0; nt < 32; ++nt) {
        const int ntr = (nt + ntoff) & 31;             // rotated sweep
        bf16x8 b0 = lBf[(ntr * 2 + 0) * 64 + lane];    // ds_read_b128, conflict-free
        bf16x8 b1 = lBf[(ntr * 2 + 1) * 64 + lane];
        f32x4 c0 = {0.0f, 0.0f, 0.0f, 0.0f};
        f32x4 c1 = {0.0f, 0.0f, 0.0f, 0.0f};
        c0 = __builtin_amdgcn_mfma_f32_16x16x32_bf16(afrag0[0], b0, c0, 0, 0, 0);
        c1 = __builtin_amdgcn_mfma_f32_16x16x32_bf16(afrag1[0], b0, c1, 0, 0, 0);
        c0 = __builtin_amdgcn_mfma_f32_16x16x32_bf16(afrag0[1], b1, c0, 0, 0, 0);
        c1 = __builtin_amdgcn_mfma_f32_16x16x32_bf16(afrag1[1], b1, c1, 0, 0, 0);
        const float    kn   = kn2p[ntr * 16 + col];    // L1-hot, shared by rows
        const unsigned kidx = (unsigned)(ntr * 16 + col);
        #pragma unroll
        for (int r = 0; r < 4; ++r) {
            float s0 = fmaf(m2r0[r], c0[r], kn);       // (~0.6, 5.2) -> uint-orderable
            unsigned key0 = (__float_as_uint(s0) & 0xFFFFFE00u) | kidx;  // 9-bit k
            unsigned mx0  = max(run1_0[r], key0);
            run1_0[r] = min(run1_0[r], key0);
            run2_0[r] = min(run2_0[r], mx0);           // 2nd-smallest key
            float s1 = fmaf(m2r1[r], c1[r], kn);
            unsigned key1 = (__float_as_uint(s1) & 0xFFFFFE00u) | kidx;
            unsigned mx1  = max(run1_1[r], key1);
            run1_1[r] = min(run1_1[r], key1);
            run2_1[r] = min(run2_1[r], mx1);
        }
    }

    // ---- thresholds per row: cross-lane min within 16-lane col group ----
    float thr0[4], thr1[4];
    #pragma unroll
    for (int r = 0; r < 4; ++r) {
        unsigned v = run1_0[r];
        v = min(v, (unsigned)__shfl_xor((int)v, 1));
        v = min(v, (unsigned)__shfl_xor((int)v, 2));
        v = min(v, (unsigned)__shfl_xor((int)v, 4));
        v = min(v, (unsigned)__shfl_xor((int)v, 8));
        thr0[r] = __uint_as_float(v & 0xFFFFFE00u) + VQ_WINDOW;
        unsigned w = run1_1[r];
        w = min(w, (unsigned)__shfl_xor((int)w, 1));
        w = min(w, (unsigned)__shfl_xor((int)w, 2));
        w = min(w, (unsigned)__shfl_xor((int)w, 4));
        w = min(w, (unsigned)__shfl_xor((int)w, 8));
        thr1[r] = __uint_as_float(w & 0xFFFFFE00u) + VQ_WINDOW;
    }

    // ---- per-row wave flags (uniform; R17's coupled flag halved) ----
    bool f0 = false, f1 = false;
    #pragma unroll
    for (int r = 0; r < 4; ++r) {
        f0 |= (__uint_as_float(run2_0[r] & 0xFFFFFE00u) <= thr0[r]);
        f1 |= (__uint_as_float(run2_1[r] & 0xFFFFFE00u) <= thr1[r]);
    }
    const bool f0w = (__ballot(f0) != 0ull);   // uniform code
    const bool f1w = (__ballot(f1) != 0ull);

    if (f0w || f1w) {
        // ---- fallback pass 2: recompute only flagged rows (uniform branches) ----
        #pragma unroll 2
        for (int nt = 0; nt < 32; ++nt) {
            const int ntr = (nt + ntoff) & 31;
            bf16x8 b0 = lBf[(ntr * 2 + 0) * 64 + lane];
            bf16x8 b1 = lBf[(ntr * 2 + 1) * 64 + lane];
            const float kn   = kn2p[ntr * 16 + col];
            const int   kidx = ntr * 16 + col;
            if (f0w) {
                f32x4 c0 = {0.0f, 0.0f, 0.0f, 0.0f};
                c0 = __builtin_amdgcn_mfma_f32_16x16x32_bf16(afrag0[0], b0, c0, 0, 0, 0);
                c0 = __builtin_amdgcn_mfma_f32_16x16x32_bf16(afrag0[1], b1, c0, 0, 0, 0);
                #pragma unroll
                for (int r = 0; r < 4; ++r) {
                    float s0 = fmaf(m2r0[r], c0[r], kn);
                    if (s0 <= thr0[r]) {
                        int pix = pbase0 + wr * 16 + quad * 4 + r;   // wave-owned
                        int pos = atomicAdd(&scnt[pix], 1);
                        if (pos < VQ_CAP) slist[pix][pos] = (unsigned short)kidx;
                    }
                }
            }
            if (f1w) {
                f32x4 c1 = {0.0f, 0.0f, 0.0f, 0.0f};
                c1 = __builtin_amdgcn_mfma_f32_16x16x32_bf16(afrag1[0], b0, c1, 0, 0, 0);
                c1 = __builtin_amdgcn_mfma_f32_16x16x32_bf16(afrag1[1], b1, c1, 0, 0, 0);
                #pragma unroll
                for (int r = 0; r < 4; ++r) {
                    float s1 = fmaf(m2r1[r], c1[r], kn);
                    if (s1 <= thr1[r]) {
                        int pix = pbase1 + wr * 16 + quad * 4 + r;
                        int pos = atomicAdd(&scnt[pix], 1);
                        if (pos < VQ_CAP) slist[pix][pos] = (unsigned short)kidx;
                    }
                }
            }
        }
    }
    if (!f0w) {
        // ---- fast path row 0: candidates are exactly the in-window slot-min1s ----
        #pragma unroll
        for (int r = 0; r < 4; ++r) {
            float s0 = __uint_as_float(run1_0[r] & 0xFFFFFE00u);
            if (s0 <= thr0[r]) {
                int pix = pbase0 + wr * 16 + quad * 4 + r;
                int pos = atomicAdd(&scnt[pix], 1);
                if (pos < VQ_CAP) slist[pix][pos] = (unsigned short)(run1_0[r] & 0x1FFu);
            }
        }
    }
    if (!f1w) {
        #pragma unroll
        for (int r = 0; r < 4; ++r) {
            float s1 = __uint_as_float(run1_1[r] & 0xFFFFFE00u);
            if (s1 <= thr1[r]) {
                int pix = pbase1 + wr * 16 + quad * 4 + r;
                int pos = atomicAdd(&scnt[pix], 1);
                if (pos < VQ_CAP) slist[pix][pos] = (unsigned short)(run1_1[r] & 0x1FFu);
            }
        }
    }
    wave_lds_fence();   // slot traffic above is same-wave only

    // ---- exact fp32 rescore, row 0 then row 1 (4 lanes/pixel, per-lane) ----
    {
        const int pw  = wr * 16 + (lane >> 2);    // this lane's rescore pixel (w)
        const int sub = lane & 3;
        {
            const int P   = pbase0 + pw;
            const int cnt = scnt[P];
            if (cnt > 1) {
                const float* xp = xblk0 + pw;
                if (cnt <= VQ_CAP) {
                    for (int i = sub; i < cnt; i += 4) {
                        const int k = slist[P][i];
                        const float* cr = cbn + (size_t)k * 64;
                        float dot = 0.0f;
                        #pragma unroll 8
                        for (int c = 0; c < 64; ++c)
                            dot = fmaf(xp[(size_t)c * 4096], cr[c], dot);  // R1 order
                        float s = fmaf(m2P0, dot, kn2[k]);
                        unsigned long long key =
                            ((unsigned long long)f2ord(s) << 32) | (unsigned)k;
                        atomicMin(&spack[P], key);
                    }
                } else {   // pathological overflow: exact scan of all codes
                    for (int k = sub; k < 512; k += 4) {
                        const float* cr = cbn + (size_t)k * 64;
                        float dot = 0.0f;
                        #pragma unroll 8
                        for (int c = 0; c < 64; ++c)
                            dot = fmaf(xp[(size_t)c * 4096], cr[c], dot);
                        float s = fmaf(m2P0, dot, kn2[k]);
                        unsigned long long key =
                            ((unsigned long long)f2ord(s) << 32) | (unsigned)k;
                        atomicMin(&spack[P], key);
                    }
                }
            }
        }
        {
            const int P   = pbase1 + pw;
            const int cnt = scnt[P];
            if (cnt > 1) {
                const float* xp = xblk1 + pw;
                if (cnt <= VQ_CAP) {
                    for (int i = sub; i < cnt; i += 4) {
                        const int k = slist[P][i];
                        const float* cr = cbn + (size_t)k * 64;
                        float dot = 0.0f;
                        #pragma unroll 8
                        for (int c = 0; c < 64; ++c)
                            dot = fmaf(xp[(size_t)c * 4096], cr[c], dot);
                        float s = fmaf(m2P1, dot, kn2[k]);
                        unsigned long long key =
                            ((unsigned long long)f2ord(s) << 32) | (unsigned)k;
                        atomicMin(&spack[P], key);
                    }
                } else {
                    for (int k = sub; k < 512; k += 4) {
                        const float* cr = cbn + (size_t)k * 64;
                        float dot = 0.0f;
                        #pragma unroll 8
                        for (int c = 0; c < 64; ++c)
                            dot = fmaf(xp[(size_t)c * 4096], cr[c], dot);
                        float s = fmaf(m2P1, dot, kn2[k]);
                        unsigned long long key =
                            ((unsigned long long)f2ord(s) << 32) | (unsigned)k;
                        atomicMin(&spack[P], key);
                    }
                }
            }
        }
    }
    wave_lds_fence();   // rescore results are same-wave too

    // ---- winners + epilogues (row 0, then row 1) ----
    {
        const int cntw = scnt[pslot0];
        const int bk = (cntw == 1) ? (int)slist[pslot0][0]
                                   : (int)(spack[pslot0] & 0xFFFFFFFFull);
        if (quad == 0) idxout[rowid0 * 64 + wpix] = (float)bk;
        const float4* crow = (const float4*)(cbn + (size_t)bk * 64) + quad * 4;
        float* cp = codes + ((size_t)b0r << 18) + (h0 << 6) + wpix;
        #pragma unroll
        for (int q = 0; q < 4; ++q) {
            float4 v = crow[q];
            const int c0 = quad * 16 + q * 4;
            cp[(size_t)(c0 + 0) * 4096] = v.x;
            cp[(size_t)(c0 + 1) * 4096] = v.y;
            cp[(size_t)(c0 + 2) * 4096] = v.z;
            cp[(size_t)(c0 + 3) * 4096] = v.w;
        }
    }
    {
        const int cntw = scnt[pslot1];
        const int bk = (cntw == 1) ? (int)slist[pslot1][0]
                                   : (int)(spack[pslot1] & 0xFFFFFFFFull);
        if (quad == 0) idxout[rowid1 * 64 + wpix] = (float)bk;
        const float4* crow = (const float4*)(cbn + (size_t)bk * 64) + quad * 4;
        float* cp = codes + ((size_t)b1r << 18) + (h1 << 6) + wpix;
        #pragma unroll
        for (int q = 0; q < 4; ++q) {
            float4 v = crow[q];
            const int c0 = quad * 16 + q * 4;
            cp[(size_t)(c0 + 0) * 4096] = v.x;
            cp[(size_t)(c0 + 1) * 4096] = v.y;
            cp[(size_t)(c0 + 2) * 4096] = v.z;
            cp[(size_t)(c0 + 3) * 4096] = v.w;
        }
    }
}

extern "C" void kernel_launch(void* const* d_in, const int* in_sizes, int n_in,
                              void* d_out, int out_size, void* d_ws, size_t ws_size,
                              hipStream_t stream) {
    const float* x  = (const float*)d_in[0];   // [32,64,64,64] fp32
    const float* cb = (const float*)d_in[1];   // [512,64] fp32

    float*          cbn  = (float*)d_ws;                       // 128 KB
    unsigned short* cbB  = (unsigned short*)(cbn + 512 * 64);  // 64 KB (frag-linear bf16)
    float*          kn2  = (float*)(cbB + 32768);              // 2 KB
    float*          kn2p = kn2 + 512;                          // 2 KB

    float* codes  = (float*)d_out;                             // 32*64*64*64 floats
    float* idxout = codes + (size_t)32 * 64 * 64 * 64;         // 131072 floats

    cb_prep_kernel<<<512, 64, 0, stream>>>(cb, cbn, cbB, kn2, kn2p);
    vq_mfma_kernel<<<256, 1024, 0, stream>>>(x, cbn, cbB, kn2, kn2p, codes, idxout);
}

// Round 9
// 115.650 us; speedup vs baseline: 1.5291x; 1.5291x over previous
//
#include <hip/hip_runtime.h>

#define VQ_EPS    1e-12f
#define VQ_WINDOW 0.01f     // >= ~14 sigma of the bf16 score error; proven R6-R10 (absmax 0)
#define VQ_CAP    12

typedef short bf16x8 __attribute__((ext_vector_type(8)));   // 8 bf16 bit-patterns = 4 VGPRs
typedef float f32x4  __attribute__((ext_vector_type(4)));

static __device__ __forceinline__ unsigned short f2bf(float f) {
    unsigned u = __float_as_uint(f);
    u += 0x7fffu + ((u >> 16) & 1u);     // RNE
    return (unsigned short)(u >> 16);
}

// Order-preserving float->uint map (handles negative exact scores).
static __device__ __forceinline__ unsigned f2ord(float f) {
    unsigned b = __float_as_uint(f);
    return (b & 0x80000000u) ? ~b : (b | 0x80000000u);
}

// Wave-local LDS fence (proven R14, absmax 0): drains this wave's DS ops and
// stops compiler reordering. Sufficient for slot traffic produced AND
// consumed by the same wave (all of scnt/slist/spack -- indices derive from
// wid only).
static __device__ __forceinline__ void wave_lds_fence() {
    asm volatile("s_waitcnt lgkmcnt(0)" ::: "memory");
}

// Single-instruction median (VOP3 v_med3_u32, GCN3+/gfx950).
static __device__ __forceinline__ unsigned umed3(unsigned a, unsigned b, unsigned c) {
    unsigned d;
    asm("v_med3_u32 %0, %1, %2, %3" : "=v"(d) : "v"(a), "v"(b), "v"(c));
    return d;
}

// Prep kernel: normalize codebook rows (fp32, mirrors F.normalize), emit:
//   cbn  [512][64] fp32      -- exact rescore + codes-gather epilogue
//   cbB  [32 ntile][2 kstep][64 lane][8] bf16 -- B-fragment-linear for
//        mfma_f32_16x16x32_bf16 (layout proven correct R5-R10)
//   kn2  [512] fp32          -- sum(cbn^2) AFTER normalization (reference rounding)
//   kn2p [512] fp32          -- kn2 + 2.0f (keeps approx scores > 0 for uint packing)
__global__ __launch_bounds__(64) void cb_prep_kernel(const float* __restrict__ cb,
                                                     float* __restrict__ cbn,
                                                     unsigned short* __restrict__ cbB,
                                                     float* __restrict__ kn2,
                                                     float* __restrict__ kn2p) {
    const int k = blockIdx.x;       // 512 codes
    const int c = threadIdx.x;      // 64 channels
    float v = cb[k * 64 + c];
    float s = v * v;
    #pragma unroll
    for (int off = 32; off > 0; off >>= 1) s += __shfl_xor(s, off, 64);
    float n = sqrtf(s);
    float cn = v / fmaxf(n, VQ_EPS);
    cbn[k * 64 + c] = cn;

    const int ntile = k >> 4, col = k & 15;
    const int ks = c >> 5, quad = (c >> 3) & 3, j = c & 7;
    cbB[(((ntile * 2 + ks) * 64) + quad * 16 + col) * 8 + j] = f2bf(cn);

    float s2 = cn * cn;
    #pragma unroll
    for (int off = 32; off > 0; off >>= 1) s2 += __shfl_xor(s2, off, 64);
    if (c == 0) { kn2[k] = s2; kn2p[k] = s2 + 2.0f; }
}

// Main kernel R19: R14 base (512 blocks x 1024 thr, 16 waves = 4 rows,
// 32 waves/CU -- best verified at 48-52 us) with ONE change: the per-slot
// running top-2 becomes a sorted TOP-3 at the SAME insertion cost
// (min + 2x v_med3_u32 = 3 ops, equal to the old max/min/min):
//   r1 = min(r1,k); r2 = med3(r1_old,k,r2); r3 = med3(r2_old,k,r3)
// Benefit: the fast path pushes ranks 1 AND 2 straight from registers, and
// the fallback re-scan fires only when a slot's 3rd-best is within the
// window (>=3 codes within 0.01 in one 32-code slot) -- rate drops from
// ~30% of waves to a few %. Candidate-set equivalence: if a slot has <3
// masked-in-window codes they are exactly ranks 1-2 (pushed); else the flag
// fires and the proven full re-scan collects everything. Masked compares
// are supersets of raw compares (positive floats) -- same proven logic.
// R18 lesson: NO extra per-thread arrays beyond +4 VGPR (run3); the 2-row
// fusion spilled to scratch under the 64-VGPR/8-wave budget and ran 2x slow.
// Safety recipe (R8/R9/R14, proven): shfls/ballot only in uniform code;
// slot init + candidate pushes wave-owned; rescore per-lane only;
// wave-local fences for same-wave slot traffic; B0 covers staging.
__global__ __launch_bounds__(1024, 8) void vq_mfma_kernel(const float* __restrict__ x,
                                                      const float* __restrict__ cbn,
                                                      const unsigned short* __restrict__ cbB,
                                                      const float* __restrict__ kn2,
                                                      const float* __restrict__ kn2p,
                                                      float* __restrict__ codes,
                                                      float* __restrict__ idxout) {
    __shared__ __align__(16) unsigned short lcb[32768];   // 64 KB staged cbB
    __shared__ unsigned long long spack[256];             // 2 KB
    __shared__ int slist[256][VQ_CAP];                    // 12 KB
    __shared__ int scnt[256];                             // 1 KB   -> 79 KB total

    const int t    = threadIdx.x;
    const int lane = t & 63;
    const int wid  = t >> 6;          // 0..15
    const int col  = lane & 15;
    const int quad = lane >> 4;
    const int wr   = wid & 3;         // wave within its row
    const int rsel = wid >> 2;        // which of the block's 4 rows
    const int wpix = wr * 16 + col;   // col-group's pixel (w coordinate)
    const int pbase = rsel * 64;      // LDS pixel-slot base for this row
    const int pslot = pbase + wpix;

    const int rowid = blockIdx.x * 4 + rsel;   // 0..2047 = (b,h)
    const int b = rowid >> 6;
    const int h = rowid & 63;
    const float* xblk = x + ((size_t)b << 18) + (h << 6);   // + c*4096 + w

    if (quad == 0) { scnt[pslot] = 0; spack[pslot] = 0xFFFFFFFFFFFFFFFFull; }

    // ---- A fragments: 16 channels of this lane's pixel, from global ----
    // (issued first so the HBM gather latency hides under the cbB staging)
    float xv[16];
    #pragma unroll
    for (int ks = 0; ks < 2; ++ks)
        #pragma unroll
        for (int j = 0; j < 8; ++j)
            xv[ks * 8 + j] = xblk[(size_t)(ks * 32 + quad * 8 + j) * 4096 + wpix];

    // ---- stage cbB -> LDS: 1024 thr x 4 x 16 B, linear, coalesced ----
    {
        const uint4* g4 = (const uint4*)cbB;
        uint4*       l4 = (uint4*)lcb;
        #pragma unroll
        for (int r = 0; r < 4; ++r) l4[r * 1024 + t] = g4[r * 1024 + t];
    }

    float ssp = 0.0f;
    #pragma unroll
    for (int i = 0; i < 16; ++i) ssp = fmaf(xv[i], xv[i], ssp);
    ssp += __shfl_xor(ssp, 16);      // uniform code: all 64 lanes execute
    ssp += __shfl_xor(ssp, 32);
    const float m2a = -2.0f * (1.0f / fmaxf(sqrtf(ssp), VQ_EPS));
    float m2r[4];
    #pragma unroll
    for (int r = 0; r < 4; ++r) m2r[r] = __shfl(m2a, quad * 4 + r);  // uniform
    const float m2P = __shfl(m2a, lane >> 2);   // uniform: m2 of rescore pixel

    bf16x8 afrag[2];
    #pragma unroll
    for (int ks = 0; ks < 2; ++ks)
        #pragma unroll
        for (int j = 0; j < 8; ++j)
            ((unsigned short*)&afrag[ks])[j] = f2bf(xv[ks * 8 + j]);

    __syncthreads();   // B0: staged cbB (and slot init) visible to all 16 waves

    const bf16x8* lBf = (const bf16x8*)lcb;

    // ---- pass 1: MFMA scan from LDS, sorted top-3 keys per (lane,r) slot ----
    unsigned run1[4] = {0xFFFFFFFFu, 0xFFFFFFFFu, 0xFFFFFFFFu, 0xFFFFFFFFu};
    unsigned run2[4] = {0xFFFFFFFFu, 0xFFFFFFFFu, 0xFFFFFFFFu, 0xFFFFFFFFu};
    unsigned run3[4] = {0xFFFFFFFFu, 0xFFFFFFFFu, 0xFFFFFFFFu, 0xFFFFFFFFu};
    #pragma unroll 4
    for (int nt = 0; nt < 32; ++nt) {
        bf16x8 b0 = lBf[(nt * 2 + 0) * 64 + lane];     // ds_read_b128, conflict-free
        bf16x8 b1 = lBf[(nt * 2 + 1) * 64 + lane];
        f32x4 c = {0.0f, 0.0f, 0.0f, 0.0f};
        c = __builtin_amdgcn_mfma_f32_16x16x32_bf16(afrag[0], b0, c, 0, 0, 0);
        c = __builtin_amdgcn_mfma_f32_16x16x32_bf16(afrag[1], b1, c, 0, 0, 0);
        const float    kn   = kn2p[nt * 16 + col];     // L1-hot
        const unsigned kidx = (unsigned)(nt * 16 + col);
        #pragma unroll
        for (int r = 0; r < 4; ++r) {
            float s = fmaf(m2r[r], c[r], kn);          // (~0.6, 5.2) -> uint-orderable
            unsigned key = (__float_as_uint(s) & 0xFFFFFE00u) | kidx;  // 9-bit k field
            unsigned o1 = run1[r], o2 = run2[r];
            run1[r] = min(o1, key);
            run2[r] = umed3(o1, key, o2);              // sorted-insert rank 2
            run3[r] = umed3(o2, key, run3[r]);         // sorted-insert rank 3
        }
    }

    // ---- thresholds: cross-lane min within each 16-lane col group (uniform) ----
    float thr[4];
    #pragma unroll
    for (int r = 0; r < 4; ++r) {
        unsigned v = run1[r];
        v = min(v, (unsigned)__shfl_xor((int)v, 1));
        v = min(v, (unsigned)__shfl_xor((int)v, 2));
        v = min(v, (unsigned)__shfl_xor((int)v, 4));
        v = min(v, (unsigned)__shfl_xor((int)v, 8));
        thr[r] = __uint_as_float(v & 0xFFFFFE00u) + VQ_WINDOW;
    }

    // ---- wave flag: any slot whose 3rd-best is within threshold? (uniform) ----
    // If not, every in-window code in every slot is among ranks 1-2, which
    // are pushed straight from registers below.
    bool f = false;
    #pragma unroll
    for (int r = 0; r < 4; ++r)
        f |= (__uint_as_float(run3[r] & 0xFFFFFE00u) <= thr[r]);
    const unsigned long long waveflag = __ballot(f);   // uniform code

    if (waveflag != 0ull) {
        // ---- fallback pass 2 (rare now): bit-identical full recompute ----
        #pragma unroll 4
        for (int nt = 0; nt < 32; ++nt) {
            bf16x8 b0 = lBf[(nt * 2 + 0) * 64 + lane];
            bf16x8 b1 = lBf[(nt * 2 + 1) * 64 + lane];
            f32x4 c = {0.0f, 0.0f, 0.0f, 0.0f};
            c = __builtin_amdgcn_mfma_f32_16x16x32_bf16(afrag[0], b0, c, 0, 0, 0);
            c = __builtin_amdgcn_mfma_f32_16x16x32_bf16(afrag[1], b1, c, 0, 0, 0);
            const float kn   = kn2p[nt * 16 + col];
            const int   kidx = nt * 16 + col;
            #pragma unroll
            for (int r = 0; r < 4; ++r) {
                float s = fmaf(m2r[r], c[r], kn);
                if (s <= thr[r]) {
                    int pix = pbase + wr * 16 + quad * 4 + r;   // wave-owned pixel
                    int pos = atomicAdd(&scnt[pix], 1);
                    if (pos < VQ_CAP) slist[pix][pos] = kidx;
                }
            }
        }
    } else {
        // ---- fast path: push in-window ranks 1 AND 2 from registers ----
        #pragma unroll
        for (int r = 0; r < 4; ++r) {
            float s1 = __uint_as_float(run1[r] & 0xFFFFFE00u);
            if (s1 <= thr[r]) {
                int pix = pbase + wr * 16 + quad * 4 + r;       // wave-owned pixel
                int pos = atomicAdd(&scnt[pix], 1);
                if (pos < VQ_CAP) slist[pix][pos] = (int)(run1[r] & 0x1FFu);
            }
            float s2 = __uint_as_float(run2[r] & 0xFFFFFE00u);
            if (s2 <= thr[r]) {
                int pix = pbase + wr * 16 + quad * 4 + r;
                int pos = atomicAdd(&scnt[pix], 1);
                if (pos < VQ_CAP) slist[pix][pos] = (int)(run2[r] & 0x1FFu);
            }
        }
    }
    wave_lds_fence();   // B1 (wave-local): slot traffic above is same-wave only

    // ---- exact fp32 rescore: 4 lanes/pixel, per-lane only (no shfl here) ----
    {
        const int pw   = wr * 16 + (lane >> 2);    // this lane's rescore pixel (w)
        const int P    = pbase + pw;               // its LDS slot
        const int sub  = lane & 3;
        const int cnt  = scnt[P];
        if (cnt > 1) {
            const float* xp = xblk + pw;
            if (cnt <= VQ_CAP) {
                for (int i = sub; i < cnt; i += 4) {
                    const int k = slist[P][i];
                    const float* cr = cbn + (size_t)k * 64;
                    float dot = 0.0f;
                    #pragma unroll 8
                    for (int c = 0; c < 64; ++c)
                        dot = fmaf(xp[(size_t)c * 4096], cr[c], dot);  // R1 order
                    float s = fmaf(m2P, dot, kn2[k]);
                    unsigned long long key =
                        ((unsigned long long)f2ord(s) << 32) | (unsigned)k;
                    atomicMin(&spack[P], key);
                }
            } else {   // pathological overflow: exact scan of all codes
                for (int k = sub; k < 512; k += 4) {
                    const float* cr = cbn + (size_t)k * 64;
                    float dot = 0.0f;
                    #pragma unroll 8
                    for (int c = 0; c < 64; ++c)
                        dot = fmaf(xp[(size_t)c * 4096], cr[c], dot);
                    float s = fmaf(m2P, dot, kn2[k]);
                    unsigned long long key =
                        ((unsigned long long)f2ord(s) << 32) | (unsigned)k;
                    atomicMin(&spack[P], key);
                }
            }
        }
    }
    wave_lds_fence();   // B2 (wave-local): rescore results are same-wave too

    // ---- winner (packed key ties break to smallest k; cnt==1 fast path) ----
    const int cntw = scnt[pslot];
    const int bk = (cntw == 1) ? slist[pslot][0]
                               : (int)(spack[pslot] & 0xFFFFFFFFull);

    if (quad == 0) idxout[rowid * 64 + wpix] = (float)bk;

    // ---- epilogue: codes[b, :, h, wpix] = cbn[bk, :]; lane writes channels
    //      quad*16 .. quad*16+15 ----
    {
        const float4* crow = (const float4*)(cbn + (size_t)bk * 64) + quad * 4;
        float* cp = codes + ((size_t)b << 18) + (h << 6) + wpix;
        #pragma unroll
        for (int q = 0; q < 4; ++q) {
            float4 v = crow[q];
            const int c0 = quad * 16 + q * 4;
            cp[(size_t)(c0 + 0) * 4096] = v.x;
            cp[(size_t)(c0 + 1) * 4096] = v.y;
            cp[(size_t)(c0 + 2) * 4096] = v.z;
            cp[(size_t)(c0 + 3) * 4096] = v.w;
        }
    }
}

extern "C" void kernel_launch(void* const* d_in, const int* in_sizes, int n_in,
                              void* d_out, int out_size, void* d_ws, size_t ws_size,
                              hipStream_t stream) {
    const float* x  = (const float*)d_in[0];   // [32,64,64,64] fp32
    const float* cb = (const float*)d_in[1];   // [512,64] fp32

    float*          cbn  = (float*)d_ws;                       // 128 KB
    unsigned short* cbB  = (unsigned short*)(cbn + 512 * 64);  // 64 KB (frag-linear bf16)
    float*          kn2  = (float*)(cbB + 32768);              // 2 KB
    float*          kn2p = kn2 + 512;                          // 2 KB

    float* codes  = (float*)d_out;                             // 32*64*64*64 floats
    float* idxout = codes + (size_t)32 * 64 * 64 * 64;         // 131072 floats

    cb_prep_kernel<<<512, 64, 0, stream>>>(cb, cbn, cbB, kn2, kn2p);
    vq_mfma_kernel<<<512, 1024, 0, stream>>>(x, cbn, cbB, kn2, kn2p, codes, idxout);
}